// Round 2
// baseline (830.937 us; speedup 1.0000x reference)
//
#include <hip/hip_runtime.h>
#include <math.h>

#define BB 64
#define SS 2048
#define HH 512
#define KK 1024
#define SCHUNK 128
#define NCHUNK (SS / SCHUNK)   // 16

__device__ __forceinline__ float fast_tanh(float x) {
    // tanh(x) = 1 - 2/(exp(2x)+1); saturates correctly for |x| large
    float e = __expf(2.0f * x);
    return 1.0f - 2.0f / (e + 1.0f);
}

// K1: q[b*HH+h] = dot(query[b,:], W_q[h,:]) — TWO outputs per wave (shared q row, 2x ILP)
__global__ __launch_bounds__(256) void qproj_kernel(
        const float* __restrict__ query,
        const float* __restrict__ Wq,
        float* __restrict__ q_out) {
    int wave = threadIdx.x >> 6;
    int lane = threadIdx.x & 63;
    int o0 = (blockIdx.x * 4 + wave) * 2;    // o = b*HH + h, o0 even so o0+1 same b
    int b = o0 >> 9;                          // / HH
    int h0 = o0 & (HH - 1);
    const float4* w0r = (const float4*)(Wq + (size_t)h0 * HH);
    const float4* w1r = (const float4*)(Wq + (size_t)(h0 + 1) * HH);
    const float4* qr  = (const float4*)(query + (size_t)b * HH);
    float a0 = 0.0f, a1 = 0.0f;
    #pragma unroll
    for (int i = 0; i < 2; ++i) {
        float4 x  = qr[lane * 2 + i];
        float4 wa = w0r[lane * 2 + i];
        float4 wb = w1r[lane * 2 + i];
        a0 += wa.x * x.x + wa.y * x.y + wa.z * x.z + wa.w * x.w;
        a1 += wb.x * x.x + wb.y * x.y + wb.z * x.z + wb.w * x.w;
    }
    #pragma unroll
    for (int off = 32; off > 0; off >>= 1) {
        a0 += __shfl_down(a0, off, 64);
        a1 += __shfl_down(a1, off, 64);
    }
    if (lane == 0) {
        q_out[o0]     = a0;
        q_out[o0 + 1] = a1;
    }
}

// K2: scores[r] = sum_h tanh(q[b,h] + pk[r,h]) * v[h] — TWO rows per wave (4 pk loads in flight)
__global__ __launch_bounds__(256) void score_kernel(
        const float* __restrict__ pk,
        const float* __restrict__ q,
        const float* __restrict__ v,
        float* __restrict__ scores) {
    int wave = threadIdx.x >> 6;
    int lane = threadIdx.x & 63;
    int r0 = (blockIdx.x * 4 + wave) * 2;    // r = b*SS + s; r0 even so r0+1 same b
    int b = r0 >> 11;                         // / SS
    const float4* p0r = (const float4*)(pk + (size_t)r0 * HH);
    const float4* p1r = (const float4*)(pk + (size_t)(r0 + 1) * HH);
    const float4* qr  = (const float4*)(q + (size_t)b * HH);
    const float4* vr  = (const float4*)v;
    float a0 = 0.0f, a1 = 0.0f;
    #pragma unroll
    for (int i = 0; i < 2; ++i) {
        float4 p0 = p0r[lane * 2 + i];
        float4 p1 = p1r[lane * 2 + i];
        float4 qq = qr[lane * 2 + i];
        float4 vv = vr[lane * 2 + i];
        a0 += fast_tanh(qq.x + p0.x) * vv.x;
        a0 += fast_tanh(qq.y + p0.y) * vv.y;
        a0 += fast_tanh(qq.z + p0.z) * vv.z;
        a0 += fast_tanh(qq.w + p0.w) * vv.w;
        a1 += fast_tanh(qq.x + p1.x) * vv.x;
        a1 += fast_tanh(qq.y + p1.y) * vv.y;
        a1 += fast_tanh(qq.z + p1.z) * vv.z;
        a1 += fast_tanh(qq.w + p1.w) * vv.w;
    }
    #pragma unroll
    for (int off = 32; off > 0; off >>= 1) {
        a0 += __shfl_down(a0, off, 64);
        a1 += __shfl_down(a1, off, 64);
    }
    if (lane == 0) {
        scores[r0]     = a0;
        scores[r0 + 1] = a1;
    }
}

// K3: masked softmax over S per b, in place (scores -> alphas). Block per b, 256 thr x 8 elems.
__global__ __launch_bounds__(256) void softmax_kernel(
        float* __restrict__ alphas,
        const int* __restrict__ mask) {
    int b = blockIdx.x;
    int t = threadIdx.x;
    float* row = alphas + (size_t)b * SS;
    const int* mrow = mask + (size_t)b * SS;
    int base = t * 8;

    float4 s0 = *(const float4*)(row + base);
    float4 s1 = *(const float4*)(row + base + 4);
    int4  m0 = *(const int4*)(mrow + base);
    int4  m1 = *(const int4*)(mrow + base + 4);
    float v[8];
    v[0] = m0.x ? s0.x : -INFINITY;
    v[1] = m0.y ? s0.y : -INFINITY;
    v[2] = m0.z ? s0.z : -INFINITY;
    v[3] = m0.w ? s0.w : -INFINITY;
    v[4] = m1.x ? s1.x : -INFINITY;
    v[5] = m1.y ? s1.y : -INFINITY;
    v[6] = m1.z ? s1.z : -INFINITY;
    v[7] = m1.w ? s1.w : -INFINITY;

    __shared__ float redmax[4];
    __shared__ float redsum[4];
    __shared__ float smax, ssum;

    float mx = v[0];
    #pragma unroll
    for (int i = 1; i < 8; ++i) mx = fmaxf(mx, v[i]);
    #pragma unroll
    for (int off = 32; off > 0; off >>= 1)
        mx = fmaxf(mx, __shfl_xor(mx, off, 64));
    if ((t & 63) == 0) redmax[t >> 6] = mx;
    __syncthreads();
    if (t == 0) smax = fmaxf(fmaxf(redmax[0], redmax[1]), fmaxf(redmax[2], redmax[3]));
    __syncthreads();
    mx = smax;

    float e[8];
    float sum = 0.0f;
    #pragma unroll
    for (int i = 0; i < 8; ++i) { e[i] = __expf(v[i] - mx); sum += e[i]; }
    #pragma unroll
    for (int off = 32; off > 0; off >>= 1)
        sum += __shfl_xor(sum, off, 64);
    if ((t & 63) == 0) redsum[t >> 6] = sum;
    __syncthreads();
    if (t == 0) ssum = redsum[0] + redsum[1] + redsum[2] + redsum[3];
    __syncthreads();
    float inv = 1.0f / ssum;

    float4 o0 = make_float4(e[0] * inv, e[1] * inv, e[2] * inv, e[3] * inv);
    float4 o1 = make_float4(e[4] * inv, e[5] * inv, e[6] * inv, e[7] * inv);
    *(float4*)(row + base)     = o0;
    *(float4*)(row + base + 4) = o1;
}

// K4a (ws path): partial context per s-chunk — NO atomics; plain float4 store to workspace.
// ws layout: partial[chunk][b][k], chunk-plane stride = BB*KK floats.
__global__ __launch_bounds__(256) void context_partial_kernel(
        const float* __restrict__ eh,
        const float* __restrict__ alphas,
        float* __restrict__ ws) {
    int chunk = blockIdx.x;
    int b = blockIdx.y;
    int t = threadIdx.x;
    __shared__ float a_sm[SCHUNK];
    if (t < SCHUNK) a_sm[t] = alphas[(size_t)b * SS + chunk * SCHUNK + t];
    __syncthreads();
    const float4* base = (const float4*)(eh + ((size_t)b * SS + (size_t)chunk * SCHUNK) * KK);
    float4 acc = make_float4(0.f, 0.f, 0.f, 0.f);
    #pragma unroll 4
    for (int s = 0; s < SCHUNK; ++s) {
        float a = a_sm[s];
        float4 x = base[(size_t)s * (KK / 4) + t];
        acc.x += a * x.x;
        acc.y += a * x.y;
        acc.z += a * x.z;
        acc.w += a * x.w;
    }
    float4* out = (float4*)(ws + (size_t)(chunk * BB + b) * KK);
    out[t] = acc;
}

// K4b (ws path): ctx[b,k] = sum over 16 chunk partials. Poison-safe single store.
__global__ __launch_bounds__(256) void context_reduce_kernel(
        const float* __restrict__ ws,
        float* __restrict__ ctx) {
    int g = blockIdx.x * 256 + threadIdx.x;   // float4 index into [BB*KK]
    const float4* w = (const float4*)ws;
    const size_t plane = (size_t)BB * KK / 4;
    float4 acc = w[g];
    #pragma unroll
    for (int c = 1; c < NCHUNK; ++c) {
        float4 x = w[(size_t)c * plane + g];
        acc.x += x.x;
        acc.y += x.y;
        acc.z += x.z;
        acc.w += x.w;
    }
    ((float4*)ctx)[g] = acc;
}

// ---- Fallback path (small/absent workspace): baseline zero + atomic context ----
__global__ __launch_bounds__(256) void zero_kernel(float* __restrict__ p, int n) {
    int i = blockIdx.x * 256 + threadIdx.x;
    if (i < n) p[i] = 0.0f;
}

__global__ __launch_bounds__(256) void context_atomic_kernel(
        const float* __restrict__ eh,
        const float* __restrict__ alphas,
        float* __restrict__ ctx) {
    int chunk = blockIdx.x;
    int b = blockIdx.y;
    int t = threadIdx.x;
    __shared__ float a_sm[SCHUNK];
    if (t < SCHUNK) a_sm[t] = alphas[(size_t)b * SS + chunk * SCHUNK + t];
    __syncthreads();
    const float4* base = (const float4*)(eh + ((size_t)b * SS + (size_t)chunk * SCHUNK) * KK);
    float4 acc = make_float4(0.f, 0.f, 0.f, 0.f);
    #pragma unroll 4
    for (int s = 0; s < SCHUNK; ++s) {
        float a = a_sm[s];
        float4 x = base[(size_t)s * (KK / 4) + t];
        acc.x += a * x.x;
        acc.y += a * x.y;
        acc.z += a * x.z;
        acc.w += a * x.w;
    }
    float* c = ctx + (size_t)b * KK + t * 4;
    atomicAdd(c + 0, acc.x);
    atomicAdd(c + 1, acc.y);
    atomicAdd(c + 2, acc.z);
    atomicAdd(c + 3, acc.w);
}

extern "C" void kernel_launch(void* const* d_in, const int* in_sizes, int n_in,
                              void* d_out, int out_size, void* d_ws, size_t ws_size,
                              hipStream_t stream) {
    const float* query    = (const float*)d_in[0];  // B x 1 x H
    const float* proj_key = (const float*)d_in[1];  // B x S x H
    const float* eh       = (const float*)d_in[2];  // B x S x K
    const int*   mask     = (const int*)  d_in[3];  // B x 1 x S
    const float* Wq       = (const float*)d_in[4];  // H x H
    const float* venergy  = (const float*)d_in[5];  // H

    float* ctx    = (float*)d_out;              // B*K = 65536 floats
    float* alphas = (float*)d_out + BB * KK;    // B*S = 131072 floats

    const size_t par_floats = (size_t)NCHUNK * BB * KK;      // 1M floats = 4 MiB
    const size_t need_bytes = (par_floats + (size_t)BB * HH) * sizeof(float);

    if (d_ws != nullptr && ws_size >= need_bytes) {
        // ---- atomic-free path: partials + q staged in workspace ----
        float* wsf    = (float*)d_ws;
        float* ws_par = wsf;
        float* q_tmp  = wsf + par_floats;

        qproj_kernel<<<(BB * HH) / 8, 256, 0, stream>>>(query, Wq, q_tmp);
        score_kernel<<<(BB * SS) / 8, 256, 0, stream>>>(proj_key, q_tmp, venergy, alphas);
        softmax_kernel<<<BB, 256, 0, stream>>>(alphas, mask);
        context_partial_kernel<<<dim3(NCHUNK, BB), 256, 0, stream>>>(eh, alphas, ws_par);
        context_reduce_kernel<<<(BB * KK) / (256 * 4), 256, 0, stream>>>(ws_par, ctx);
    } else {
        // ---- fallback: q staged in ctx region, zero + atomic accumulation ----
        float* q_tmp = ctx;
        qproj_kernel<<<(BB * HH) / 8, 256, 0, stream>>>(query, Wq, q_tmp);
        score_kernel<<<(BB * SS) / 8, 256, 0, stream>>>(proj_key, q_tmp, venergy, alphas);
        softmax_kernel<<<BB, 256, 0, stream>>>(alphas, mask);
        zero_kernel<<<(BB * KK) / 256, 256, 0, stream>>>(ctx, BB * KK);
        context_atomic_kernel<<<dim3(NCHUNK, BB), 256, 0, stream>>>(eh, alphas, ctx);
    }
}